// Round 1
// 1054.500 us; speedup vs baseline: 1.0356x; 1.0356x over previous
//
#include <hip/hip_runtime.h>

#define BROWS 16384
#define DIN   4096
#define NOUT  4096
#define EPSV  1e-5f
#define KT    (DIN / 64)

typedef __attribute__((ext_vector_type(8))) short short8;
typedef __attribute__((ext_vector_type(4))) float f32x4;

__device__ __forceinline__ unsigned short f32_to_bf16(float f) {
    union { float f; unsigned u; } v;
    v.f = f;
    unsigned r = (v.u + 0x7fffu + ((v.u >> 16) & 1u)) >> 16;  // RNE
    return (unsigned short)r;
}

// ---------------- Kernel 1: row L2-normalize + cast to bf16 ----------------
__global__ __launch_bounds__(256) void normalize_cast_kernel(
    const float* __restrict__ x, unsigned short* __restrict__ A) {
    const int row = blockIdx.x;
    const int tid = threadIdx.x;
    const float4* xr = (const float4*)(x + (size_t)row * DIN);
    float4 v[4];
    float ss = 0.f;
#pragma unroll
    for (int i = 0; i < 4; ++i) {
        v[i] = xr[tid + i * 256];
        ss += v[i].x * v[i].x + v[i].y * v[i].y + v[i].z * v[i].z + v[i].w * v[i].w;
    }
#pragma unroll
    for (int o = 32; o > 0; o >>= 1) ss += __shfl_down(ss, o);
    __shared__ float red[4];
    const int wave = tid >> 6, lane = tid & 63;
    if (lane == 0) red[wave] = ss;
    __syncthreads();
    const float inv = 1.f / (sqrtf(red[0] + red[1] + red[2] + red[3]) + EPSV);
    uint2* Ar = (uint2*)(A + (size_t)row * DIN);
#pragma unroll
    for (int i = 0; i < 4; ++i) {
        uint2 p;
        p.x = (unsigned)f32_to_bf16(v[i].x * inv) | ((unsigned)f32_to_bf16(v[i].y * inv) << 16);
        p.y = (unsigned)f32_to_bf16(v[i].z * inv) | ((unsigned)f32_to_bf16(v[i].w * inv) << 16);
        Ar[tid + i * 256] = p;
    }
}

// ---------------- Kernel 2: W[k][n] fp32 -> Wt[n][k] bf16, 64x64 tiles ----------------
__global__ __launch_bounds__(256) void transpose_cast_kernel(
    const float* __restrict__ W, unsigned short* __restrict__ Wt) {
    __shared__ float tile[64][65];  // +1 pad: conflict-free transposed read
    const int bn = blockIdx.x * 64, bk = blockIdx.y * 64;
    const int t = threadIdx.x;
    const int lk = t >> 4, ln4 = (t & 15) * 4;
#pragma unroll
    for (int i = 0; i < 4; ++i) {
        float4 v = *(const float4*)(W + (size_t)(bk + lk + i * 16) * NOUT + bn + ln4);
        tile[lk + i * 16][ln4 + 0] = v.x;
        tile[lk + i * 16][ln4 + 1] = v.y;
        tile[lk + i * 16][ln4 + 2] = v.z;
        tile[lk + i * 16][ln4 + 3] = v.w;
    }
    __syncthreads();
    const int ln = t >> 4, lk4 = (t & 15) * 4;
#pragma unroll
    for (int i = 0; i < 4; ++i) {
        const int n = ln + i * 16;
        uint2 p;
        p.x = (unsigned)f32_to_bf16(tile[lk4 + 0][n]) | ((unsigned)f32_to_bf16(tile[lk4 + 1][n]) << 16);
        p.y = (unsigned)f32_to_bf16(tile[lk4 + 2][n]) | ((unsigned)f32_to_bf16(tile[lk4 + 3][n]) << 16);
        *(uint2*)(Wt + (size_t)(bn + n) * DIN + bk + lk4) = p;  // 128B/row segments
    }
}

// ---------------- Kernel 3: C = relu(A @ W + b), 256x256 8-phase bf16 MFMA ----------------
// A [M,K] bf16 row-major; Wt [N,K] bf16 (k contiguous); C [M,N] fp32.
// 256x256 tile, BK=64, 512 threads = 8 waves (2M x 4N), 128x64 output per wave.
// LDS 128 KiB: 2 dbuf x (A 256x64 + B 256x64) bf16. K-tile kt lives in buf kt&1.
// Swizzle: LDS slot p (of 8 x 16B chunks per 128B row) holds global k-chunk
// p ^ ((row&15)>>1) -> ds_read_b128 fragments spread uniformly over all 32 banks
// (same scheme as prior kernel, which measured 0 bank conflicts).
//
// 8-phase schedule per 2 K-tiles (4 phases per K-tile K, cur = K&1):
//  P0: dsr a0[8]+b0[4](ks0); stage Ah1(K+1)->!cur; bar; lgkm0; prio1; mfma i0-3 ks0; prio0; bar
//  P1: dsr b1[4](ks1);                             bar; lgkm0; prio1; mfma i4-7 ks0; prio0; bar
//  P2: dsr a1[8](ks1); stage Bh0,Bh1(K+2)->cur;    bar; lgkm0; prio1; mfma i0-3 ks1; prio0; bar
//  P3: stage Ah0(K+2)->cur; vmcnt(6); bar; prio1;             mfma i4-7 ks1; prio0; bar
// Race-freedom: each phase's ds_reads complete before its end barrier (explicit
// lgkmcnt(0)), and every stage targets a region whose last reads were in a
// strictly earlier phase (A reads end P2, staged P3/P0'; B reads end P1, staged P2).
// vmcnt(6) = 3 half-tiles (Bh0,Bh1,Ah0 of K+2) stay in flight across the barrier;
// never drained to 0 inside the loop.

__device__ __forceinline__ void async_copy16(const unsigned short* g, unsigned short* l) {
    __builtin_amdgcn_global_load_lds(
        (const __attribute__((address_space(1))) unsigned int*)g,
        (__attribute__((address_space(3))) unsigned int*)l, 16, 0, 0);
}

__global__ __launch_bounds__(512, 2) void gemm_bias_relu_kernel(
    const unsigned short* __restrict__ A, const unsigned short* __restrict__ Wt,
    const float* __restrict__ bias, float* __restrict__ C) {
    __shared__ __align__(16) unsigned short As[2][256 * 64];
    __shared__ __align__(16) unsigned short Bs[2][256 * 64];

    const int tid = threadIdx.x;
    const int lane = tid & 63, wave = tid >> 6;
    const int wm = wave >> 2, wn = wave & 3;       // 2 x 4 wave grid
    const int lm = lane & 15, q = lane >> 4;
    const int ko0 = (q ^ (lm >> 1)) * 8;           // ks0 chunk offset (shorts)
    const int ko1 = ko0 ^ 32;                      // ks1 = chunk index ^4

    // XCD-aware bijective swizzle (1024 blocks % 8 == 0)
    const int bid = (int)blockIdx.x;
    const int wg = (bid & 7) * 128 + (bid >> 3);
    const int n0 = (wg & 15) * 256;                // n fastest within XCD chunk
    const int m0 = (wg >> 4) * 256;

    // staging: thread t covers 16B chunks t and t+512 of each 128x64 half-tile.
    // chunk c: row r = c>>3, slot p = c&7 holds global k-chunk p ^ ((r&15)>>1).
    const int r0 = tid >> 3;
    const int g0 = (tid & 7) ^ ((r0 & 15) >> 1);
    const unsigned short* Ag = A + (size_t)(m0 + r0) * DIN + g0 * 8;
    const unsigned short* Bg = Wt + (size_t)(n0 + r0) * DIN + g0 * 8;
    const int ub = (tid & ~63) * 8;                // wave-uniform LDS base (shorts)

#define STG_A(buf, half, kk) do { \
    const unsigned short* s_ = Ag + (size_t)(half) * (128 * DIN) + (kk); \
    unsigned short* d_ = &As[buf][(half) * 8192 + ub]; \
    async_copy16(s_, d_); \
    async_copy16(s_ + 64 * DIN, d_ + 4096); \
} while (0)
#define STG_B(buf, half, kk) do { \
    const unsigned short* s_ = Bg + (size_t)(half) * (128 * DIN) + (kk); \
    unsigned short* d_ = &Bs[buf][(half) * 8192 + ub]; \
    async_copy16(s_, d_); \
    async_copy16(s_ + 64 * DIN, d_ + 4096); \
} while (0)

    f32x4 acc[8][4] = {};

    // prologue: K0 fully + K1 {Bh0,Bh1,Ah0}; K1's Ah1 is staged at P0 of kt=0
    STG_B(0, 0, 0);  STG_B(0, 1, 0);
    STG_A(0, 0, 0);  STG_A(0, 1, 0);
    STG_B(1, 0, 64); STG_B(1, 1, 64);
    STG_A(1, 0, 64);
    asm volatile("s_waitcnt vmcnt(6)" ::: "memory");  // K0's 8 loads landed
    __builtin_amdgcn_s_barrier();
    __builtin_amdgcn_sched_barrier(0);

#pragma unroll 2
    for (int kt = 0; kt < KT; ++kt) {
        const int cur = kt & 1;
        const int kb1 = (kt + 1 < KT ? kt + 1 : KT - 1) * 64;  // clamped tail stages:
        const int kb2 = (kt + 2 < KT ? kt + 2 : KT - 1) * 64;  // land in dead regions
        const unsigned short* as = As[cur];
        const unsigned short* bs = Bs[cur];

        short8 a0[8], a1[8], b0[4], b1[4];

        // ---- phase 0 ----
#pragma unroll
        for (int i = 0; i < 8; ++i)
            a0[i] = *(const short8*)&as[(wm * 128 + i * 16 + lm) * 64 + ko0];
#pragma unroll
        for (int j = 0; j < 4; ++j)
            b0[j] = *(const short8*)&bs[(wn * 64 + j * 16 + lm) * 64 + ko0];
        STG_A(cur ^ 1, 1, kb1);                    // Ah1(K+1): region free since P2(K-1)
        __builtin_amdgcn_s_barrier();
        asm volatile("s_waitcnt lgkmcnt(0)" ::: "memory");
        __builtin_amdgcn_s_setprio(1);
#pragma unroll
        for (int i = 0; i < 4; ++i)
#pragma unroll
            for (int j = 0; j < 4; ++j)
                acc[i][j] = __builtin_amdgcn_mfma_f32_16x16x32_bf16(a0[i], b0[j], acc[i][j], 0, 0, 0);
        __builtin_amdgcn_s_setprio(0);
        __builtin_amdgcn_s_barrier();

        // ---- phase 1 ----
#pragma unroll
        for (int j = 0; j < 4; ++j)
            b1[j] = *(const short8*)&bs[(wn * 64 + j * 16 + lm) * 64 + ko1];
        __builtin_amdgcn_s_barrier();
        asm volatile("s_waitcnt lgkmcnt(0)" ::: "memory");  // all B reads of K done here
        __builtin_amdgcn_s_setprio(1);
#pragma unroll
        for (int i = 4; i < 8; ++i)
#pragma unroll
            for (int j = 0; j < 4; ++j)
                acc[i][j] = __builtin_amdgcn_mfma_f32_16x16x32_bf16(a0[i], b0[j], acc[i][j], 0, 0, 0);
        __builtin_amdgcn_s_setprio(0);
        __builtin_amdgcn_s_barrier();

        // ---- phase 2 ----
#pragma unroll
        for (int i = 0; i < 8; ++i)
            a1[i] = *(const short8*)&as[(wm * 128 + i * 16 + lm) * 64 + ko1];
        STG_B(cur, 0, kb2);                        // B regions of cur freed at end P1
        STG_B(cur, 1, kb2);
        __builtin_amdgcn_s_barrier();
        asm volatile("s_waitcnt lgkmcnt(0)" ::: "memory");  // all A reads of K done here
        __builtin_amdgcn_s_setprio(1);
#pragma unroll
        for (int i = 0; i < 4; ++i)
#pragma unroll
            for (int j = 0; j < 4; ++j)
                acc[i][j] = __builtin_amdgcn_mfma_f32_16x16x32_bf16(a1[i], b1[j], acc[i][j], 0, 0, 0);
        __builtin_amdgcn_s_setprio(0);
        __builtin_amdgcn_s_barrier();

        // ---- phase 3 ----
        STG_A(cur, 0, kb2);                        // Ah0(K+2): A of cur freed at end P2
        asm volatile("s_waitcnt vmcnt(6)" ::: "memory");  // K+1 fully landed; 3 half-tiles stay in flight
        __builtin_amdgcn_s_barrier();
        __builtin_amdgcn_s_setprio(1);
#pragma unroll
        for (int i = 4; i < 8; ++i)
#pragma unroll
            for (int j = 0; j < 4; ++j)
                acc[i][j] = __builtin_amdgcn_mfma_f32_16x16x32_bf16(a1[i], b1[j], acc[i][j], 0, 0, 0);
        __builtin_amdgcn_s_setprio(0);
        __builtin_amdgcn_s_barrier();
        __builtin_amdgcn_sched_barrier(0);         // pin next K-tile's ds_reads below this point
    }

    asm volatile("s_waitcnt vmcnt(0)" ::: "memory");  // drain tail stages before LDS dealloc

    // epilogue: C/D layout col=lane&15, row=(lane>>4)*4+reg  [m89/m91]
    float bj[4];
#pragma unroll
    for (int j = 0; j < 4; ++j) bj[j] = bias[n0 + wn * 64 + j * 16 + lm];
    const int colb = n0 + wn * 64 + lm;
    const int rowb = m0 + wm * 128 + (q << 2);
#pragma unroll
    for (int i = 0; i < 8; ++i) {
#pragma unroll
        for (int r = 0; r < 4; ++r) {
            float* cp = C + (size_t)(rowb + i * 16 + r) * NOUT + colb;
#pragma unroll
            for (int j = 0; j < 4; ++j) {
                float v = acc[i][j][r] + bj[j];
                __builtin_nontemporal_store(v > 0.f ? v : 0.f, cp + j * 16);
            }
        }
    }
#undef STG_A
#undef STG_B
}

extern "C" void kernel_launch(void* const* d_in, const int* in_sizes, int n_in,
                              void* d_out, int out_size, void* d_ws, size_t ws_size,
                              hipStream_t stream) {
    const float* x = (const float*)d_in[0];
    const float* W = (const float*)d_in[1];
    const float* b = (const float*)d_in[2];
    float* out = (float*)d_out;

    // ws layout: A_bf16 [16384*4096] (128 MiB) | Wt_bf16 [4096*4096] (32 MiB)
    unsigned short* Abf = (unsigned short*)d_ws;
    unsigned short* Wt = Abf + (size_t)BROWS * DIN;

    normalize_cast_kernel<<<BROWS, 256, 0, stream>>>(x, Abf);
    transpose_cast_kernel<<<dim3(NOUT / 64, DIN / 64), 256, 0, stream>>>(W, Wt);
    gemm_bias_relu_kernel<<<dim3(NOUT / 256 * (BROWS / 256)), 512, 0, stream>>>(Abf, Wt, b, out);
}

// Round 2
// 1040.109 us; speedup vs baseline: 1.0499x; 1.0138x over previous
//
#include <hip/hip_runtime.h>

#define BROWS 16384
#define DIN   4096
#define NOUT  4096
#define EPSV  1e-5f
#define KT    (DIN / 64)

typedef __attribute__((ext_vector_type(8))) short short8;
typedef __attribute__((ext_vector_type(4))) float f32x4;

__device__ __forceinline__ unsigned short f32_to_bf16(float f) {
    union { float f; unsigned u; } v;
    v.f = f;
    unsigned r = (v.u + 0x7fffu + ((v.u >> 16) & 1u)) >> 16;  // RNE
    return (unsigned short)r;
}

// ---------------- Kernel 1: row L2-normalize + cast to bf16 ----------------
__global__ __launch_bounds__(256) void normalize_cast_kernel(
    const float* __restrict__ x, unsigned short* __restrict__ A) {
    const int row = blockIdx.x;
    const int tid = threadIdx.x;
    const float4* xr = (const float4*)(x + (size_t)row * DIN);
    float4 v[4];
    float ss = 0.f;
#pragma unroll
    for (int i = 0; i < 4; ++i) {
        v[i] = xr[tid + i * 256];
        ss += v[i].x * v[i].x + v[i].y * v[i].y + v[i].z * v[i].z + v[i].w * v[i].w;
    }
#pragma unroll
    for (int o = 32; o > 0; o >>= 1) ss += __shfl_down(ss, o);
    __shared__ float red[4];
    const int wave = tid >> 6, lane = tid & 63;
    if (lane == 0) red[wave] = ss;
    __syncthreads();
    const float inv = 1.f / (sqrtf(red[0] + red[1] + red[2] + red[3]) + EPSV);
    uint2* Ar = (uint2*)(A + (size_t)row * DIN);
#pragma unroll
    for (int i = 0; i < 4; ++i) {
        uint2 p;
        p.x = (unsigned)f32_to_bf16(v[i].x * inv) | ((unsigned)f32_to_bf16(v[i].y * inv) << 16);
        p.y = (unsigned)f32_to_bf16(v[i].z * inv) | ((unsigned)f32_to_bf16(v[i].w * inv) << 16);
        Ar[tid + i * 256] = p;
    }
}

// ---------------- Kernel 2: W[k][n] fp32 -> Wt[n][k] bf16, 64x64 tiles ----------------
__global__ __launch_bounds__(256) void transpose_cast_kernel(
    const float* __restrict__ W, unsigned short* __restrict__ Wt) {
    __shared__ float tile[64][65];  // +1 pad: conflict-free transposed read
    const int bn = blockIdx.x * 64, bk = blockIdx.y * 64;
    const int t = threadIdx.x;
    const int lk = t >> 4, ln4 = (t & 15) * 4;
#pragma unroll
    for (int i = 0; i < 4; ++i) {
        float4 v = *(const float4*)(W + (size_t)(bk + lk + i * 16) * NOUT + bn + ln4);
        tile[lk + i * 16][ln4 + 0] = v.x;
        tile[lk + i * 16][ln4 + 1] = v.y;
        tile[lk + i * 16][ln4 + 2] = v.z;
        tile[lk + i * 16][ln4 + 3] = v.w;
    }
    __syncthreads();
    const int ln = t >> 4, lk4 = (t & 15) * 4;
#pragma unroll
    for (int i = 0; i < 4; ++i) {
        const int n = ln + i * 16;
        uint2 p;
        p.x = (unsigned)f32_to_bf16(tile[lk4 + 0][n]) | ((unsigned)f32_to_bf16(tile[lk4 + 1][n]) << 16);
        p.y = (unsigned)f32_to_bf16(tile[lk4 + 2][n]) | ((unsigned)f32_to_bf16(tile[lk4 + 3][n]) << 16);
        *(uint2*)(Wt + (size_t)(bn + n) * DIN + bk + lk4) = p;  // 128B/row segments
    }
}

// ---------------- Kernel 3: C = relu(A @ W + b), 256x256 8-phase bf16 MFMA ----------------
// Balanced m201-template port. 256x256 tile, BK=64, 8 waves (2M x 4N), 128x64/wave.
// Frags per K-tile per wave: aA(i0-3,ks0) aB(i4-7,ks0) aC(i0-3,ks1) aD(i4-7,ks1) b0(ks0) b1(ks1).
// Phase schedule per K-tile T (cur=T&1):
//  P0: read aA+b0 (8 dsr); stage Bh1(T+1)->nxt;     bar; lgkm0; prio1; mfma(aA,b0)->acc[0-3]; prio0; bar
//  P1: read aB+aD (8 dsr);                           bar; lgkm0; prio1; mfma(aB,b0)->acc[4-7]; prio0; bar
//  P2: read aC+b1 (8 dsr); stage Ah0(T+2)->cur;     bar; lgkm0; prio1; mfma(aC,b1)->acc[0-3]; prio0; bar
//  P3: stage Ah1+Bh0(T+2)->cur; vmcnt(6);           bar;        prio1; mfma(aD,b1)->acc[4-7]; prio0; bar
// Reads: 8/8/8/0 (template: 4-or-8/phase). Stages: 1/0/1/2 half-tiles. vmcnt(6) = exactly
// 3 half-tiles in flight (template value), once per K-tile.
// Race-freedom: (1) each phase's reads complete before its end barrier (lgkmcnt(0) pre-MFMA);
// every stage targets a region whose last read was in a strictly earlier phase
// (A-region last read P1 -> staged P2/P3; B-region last read P2 -> staged P3/P0').
// (2) beta(T+2) stages {Ah0@P2(T), Ah1+Bh0@P3(T), Bh1@P0(T+1)} are forced-landed by every
// wave's vmcnt(6) at P3(T+1) (its 6 allowed-outstanding are all beta(T+3) stages), which
// precedes the end-P3(T+1) barrier, which precedes the first beta(T+2) reads at P0(T+2):
// the barrier transfers each wave's per-wave vmcnt guarantee to all waves.

__device__ __forceinline__ void async_copy16(const unsigned short* g, unsigned short* l) {
    __builtin_amdgcn_global_load_lds(
        (const __attribute__((address_space(1))) unsigned int*)g,
        (__attribute__((address_space(3))) unsigned int*)l, 16, 0, 0);
}

__global__ __launch_bounds__(512, 2) void gemm_bias_relu_kernel(
    const unsigned short* __restrict__ A, const unsigned short* __restrict__ Wt,
    const float* __restrict__ bias, float* __restrict__ C) {
    __shared__ __align__(16) unsigned short As[2][256 * 64];
    __shared__ __align__(16) unsigned short Bs[2][256 * 64];

    const int tid = threadIdx.x;
    const int lane = tid & 63, wave = tid >> 6;
    const int wm = wave >> 2, wn = wave & 3;       // 2 x 4 wave grid
    const int lm = lane & 15, q = lane >> 4;
    const int ko0 = (q ^ (lm >> 1)) * 8;           // ks0 chunk offset (shorts)
    const int ko1 = ko0 ^ 32;                      // ks1 chunk (= chunk^4)

    // XCD-aware bijective swizzle (1024 blocks % 8 == 0)
    const int bid = (int)blockIdx.x;
    const int wg = (bid & 7) * 128 + (bid >> 3);
    const int n0 = (wg & 15) * 256;
    const int m0 = (wg >> 4) * 256;

    // staging: thread t covers 16B chunks t and t+512 of each 128x64 half-tile.
    // chunk c: row r = c>>3, slot p = c&7 holds global k-chunk p ^ ((r&15)>>1).
    const int r0 = tid >> 3;
    const int g0 = (tid & 7) ^ ((r0 & 15) >> 1);
    const unsigned short* Ag = A + (size_t)(m0 + r0) * DIN + g0 * 8;
    const unsigned short* Bg = Wt + (size_t)(n0 + r0) * DIN + g0 * 8;
    const int ub = (tid & ~63) * 8;                // wave-uniform LDS base (shorts)

#define STG_A(buf, half, kk) do { \
    const unsigned short* s_ = Ag + (size_t)(half) * (128 * DIN) + (kk); \
    unsigned short* d_ = &As[buf][(half) * 8192 + ub]; \
    async_copy16(s_, d_); \
    async_copy16(s_ + 64 * DIN, d_ + 4096); \
} while (0)
#define STG_B(buf, half, kk) do { \
    const unsigned short* s_ = Bg + (size_t)(half) * (128 * DIN) + (kk); \
    unsigned short* d_ = &Bs[buf][(half) * 8192 + ub]; \
    async_copy16(s_, d_); \
    async_copy16(s_ + 64 * DIN, d_ + 4096); \
} while (0)

    f32x4 acc[8][4] = {};

    // prologue: beta0 all 4 halves (8 loads) + beta1 {Ah0,Ah1,Bh0} (6 loads);
    // vmcnt(6) forces beta0 landed, leaves exactly the steady-state 6 in flight.
    STG_A(0, 0, 0);  STG_A(0, 1, 0);
    STG_B(0, 0, 0);  STG_B(0, 1, 0);
    STG_A(1, 0, 64); STG_A(1, 1, 64);
    STG_B(1, 0, 64);
    asm volatile("s_waitcnt vmcnt(6)" ::: "memory");
    __builtin_amdgcn_s_barrier();
    __builtin_amdgcn_sched_barrier(0);

#pragma unroll 2
    for (int kt = 0; kt < KT; ++kt) {
        const int cur = kt & 1;
        const int kb1 = (kt + 1 < KT ? kt + 1 : KT - 1) * 64;  // clamped tail stages
        const int kb2 = (kt + 2 < KT ? kt + 2 : KT - 1) * 64;  // land in dead regions
        const unsigned short* as = As[cur];
        const unsigned short* bs = Bs[cur];

        short8 aA[4], aB[4], aC[4], aD[4], b0[4], b1[4];

        // ---- phase 0: 8 dsr + 1 half stage + 16 mfma ----
#pragma unroll
        for (int i = 0; i < 4; ++i)
            aA[i] = *(const short8*)&as[(wm * 128 + i * 16 + lm) * 64 + ko0];
#pragma unroll
        for (int j = 0; j < 4; ++j)
            b0[j] = *(const short8*)&bs[(wn * 64 + j * 16 + lm) * 64 + ko0];
        STG_B(cur ^ 1, 1, kb1);                    // Bh1(T+1): region free since P2(T-1)
        __builtin_amdgcn_s_barrier();
        asm volatile("s_waitcnt lgkmcnt(0)" ::: "memory");
        __builtin_amdgcn_s_setprio(1);
#pragma unroll
        for (int i = 0; i < 4; ++i)
#pragma unroll
            for (int j = 0; j < 4; ++j)
                acc[i][j] = __builtin_amdgcn_mfma_f32_16x16x32_bf16(aA[i], b0[j], acc[i][j], 0, 0, 0);
        __builtin_amdgcn_s_setprio(0);
        __builtin_amdgcn_s_barrier();
        __builtin_amdgcn_sched_barrier(0);

        // ---- phase 1: 8 dsr + 16 mfma ----
#pragma unroll
        for (int i = 0; i < 4; ++i)
            aB[i] = *(const short8*)&as[(wm * 128 + (i + 4) * 16 + lm) * 64 + ko0];
#pragma unroll
        for (int i = 0; i < 4; ++i)
            aD[i] = *(const short8*)&as[(wm * 128 + (i + 4) * 16 + lm) * 64 + ko1];
        __builtin_amdgcn_s_barrier();
        asm volatile("s_waitcnt lgkmcnt(0)" ::: "memory");
        __builtin_amdgcn_s_setprio(1);
#pragma unroll
        for (int i = 0; i < 4; ++i)
#pragma unroll
            for (int j = 0; j < 4; ++j)
                acc[4 + i][j] = __builtin_amdgcn_mfma_f32_16x16x32_bf16(aB[i], b0[j], acc[4 + i][j], 0, 0, 0);
        __builtin_amdgcn_s_setprio(0);
        __builtin_amdgcn_s_barrier();
        __builtin_amdgcn_sched_barrier(0);

        // ---- phase 2: 8 dsr + 1 half stage + 16 mfma ----
#pragma unroll
        for (int i = 0; i < 4; ++i)
            aC[i] = *(const short8*)&as[(wm * 128 + i * 16 + lm) * 64 + ko1];
#pragma unroll
        for (int j = 0; j < 4; ++j)
            b1[j] = *(const short8*)&bs[(wn * 64 + j * 16 + lm) * 64 + ko1];
        STG_A(cur, 0, kb2);                        // Ah0(T+2): A-region free since P1
        __builtin_amdgcn_s_barrier();
        asm volatile("s_waitcnt lgkmcnt(0)" ::: "memory");
        __builtin_amdgcn_s_setprio(1);
#pragma unroll
        for (int i = 0; i < 4; ++i)
#pragma unroll
            for (int j = 0; j < 4; ++j)
                acc[i][j] = __builtin_amdgcn_mfma_f32_16x16x32_bf16(aC[i], b1[j], acc[i][j], 0, 0, 0);
        __builtin_amdgcn_s_setprio(0);
        __builtin_amdgcn_s_barrier();
        __builtin_amdgcn_sched_barrier(0);

        // ---- phase 3: 2 half stages + vmcnt(6) + 16 mfma ----
        STG_A(cur, 1, kb2);                        // Ah1(T+2): A-region free since P1
        STG_B(cur, 0, kb2);                        // Bh0(T+2): B-region free since P2
        asm volatile("s_waitcnt vmcnt(6)" ::: "memory");  // forces beta(T+1) fully landed
        __builtin_amdgcn_s_barrier();
        __builtin_amdgcn_s_setprio(1);
#pragma unroll
        for (int i = 0; i < 4; ++i)
#pragma unroll
            for (int j = 0; j < 4; ++j)
                acc[4 + i][j] = __builtin_amdgcn_mfma_f32_16x16x32_bf16(aD[i], b1[j], acc[4 + i][j], 0, 0, 0);
        __builtin_amdgcn_s_setprio(0);
        __builtin_amdgcn_s_barrier();
        __builtin_amdgcn_sched_barrier(0);
    }

    asm volatile("s_waitcnt vmcnt(0)" ::: "memory");  // drain tail stages before exit

    // epilogue: C/D layout col=lane&15, row=(lane>>4)*4+reg  [m89/m91]
    float bj[4];
#pragma unroll
    for (int j = 0; j < 4; ++j) bj[j] = bias[n0 + wn * 64 + j * 16 + lm];
    const int colb = n0 + wn * 64 + lm;
    const int rowb = m0 + wm * 128 + (q << 2);
#pragma unroll
    for (int i = 0; i < 8; ++i) {
#pragma unroll
        for (int r = 0; r < 4; ++r) {
            float* cp = C + (size_t)(rowb + i * 16 + r) * NOUT + colb;
#pragma unroll
            for (int j = 0; j < 4; ++j) {
                float v = acc[i][j][r] + bj[j];
                __builtin_nontemporal_store(v > 0.f ? v : 0.f, cp + j * 16);
            }
        }
    }
#undef STG_A
#undef STG_B
}

extern "C" void kernel_launch(void* const* d_in, const int* in_sizes, int n_in,
                              void* d_out, int out_size, void* d_ws, size_t ws_size,
                              hipStream_t stream) {
    const float* x = (const float*)d_in[0];
    const float* W = (const float*)d_in[1];
    const float* b = (const float*)d_in[2];
    float* out = (float*)d_out;

    // ws layout: A_bf16 [16384*4096] (128 MiB) | Wt_bf16 [4096*4096] (32 MiB)
    unsigned short* Abf = (unsigned short*)d_ws;
    unsigned short* Wt = Abf + (size_t)BROWS * DIN;

    normalize_cast_kernel<<<BROWS, 256, 0, stream>>>(x, Abf);
    transpose_cast_kernel<<<dim3(NOUT / 64, DIN / 64), 256, 0, stream>>>(W, Wt);
    gemm_bias_relu_kernel<<<dim3(NOUT / 256 * (BROWS / 256)), 512, 0, stream>>>(Abf, Wt, b, out);
}